// Round 6
// baseline (334.740 us; speedup 1.0000x reference)
//
#include <hip/hip_runtime.h>
#include <hip/hip_bf16.h>
#include <stdint.h>

#if __has_builtin(__builtin_amdgcn_cvt_pk_f32_fp8) && __has_builtin(__builtin_amdgcn_cvt_pk_fp8_f32)
#define FP8_HW 1
#else
#define FP8_HW 0
#include <hip/hip_fp8.h>
#endif

#define N_NODES 100000
#define N_EDGES 1600000
#define FEAT 128

#define BKT_SHIFT 8
#define BKT_SIZE  256
#define NB_BKT    391          // ceil(N_NODES / 256)
#define BKT_CAP   5664         // pad-8 mean 4982 + >9-sigma headroom, mult of 8
#define NB_SC     800          // blocks in edge passes
#define EPB_SC    2000         // edges per block (800*2000 = 1.6M exactly)

#define PREP_CVT 6250          // cvt_x8 blocks (6250*256 = 1.6M rows of 8 floats)
#define PREP_W   192           // wprep blocks
#define PREP_H   800           // hist blocks

typedef uint16_t u16;
typedef uint32_t u32;
typedef __attribute__((ext_vector_type(8))) short bf16x8;
typedef __attribute__((ext_vector_type(4))) float f32x4;
typedef __attribute__((ext_vector_type(2))) float f32x2;

__device__ __forceinline__ u16 bf16_rn(float f){
  u32 u = __float_as_uint(f);
  u += 0x7FFFu + ((u >> 16) & 1u);
  return (u16)(u >> 16);
}
__device__ __forceinline__ float bf16_lo(u32 p){ return __uint_as_float(p << 16); }
__device__ __forceinline__ float bf16_hi(u32 p){ return __uint_as_float(p & 0xFFFF0000u); }

__device__ __forceinline__ void fp8x4_to_f32(u32 w, float* o){
#if FP8_HW
  f32x2 a = __builtin_amdgcn_cvt_pk_f32_fp8(w, false);
  f32x2 b = __builtin_amdgcn_cvt_pk_f32_fp8(w, true);
  o[0] = a.x; o[1] = a.y; o[2] = b.x; o[3] = b.y;
#else
  #pragma unroll
  for (int i = 0; i < 4; ++i){
    __hip_fp8_e4m3 t; t.__x = (uint8_t)((w >> (8 * i)) & 0xFF);
    o[i] = (float)t;
  }
#endif
}
__device__ __forceinline__ u32 f32x4_to_fp8(float a, float b, float c, float d){
#if FP8_HW
  u32 r = __builtin_amdgcn_cvt_pk_fp8_f32(a, b, 0, false);
  r = __builtin_amdgcn_cvt_pk_fp8_f32(c, d, r, true);
  return r;
#else
  __hip_fp8_e4m3 qa(a), qb(b), qc(c), qd(d);
  return (u32)qa.__x | ((u32)qb.__x << 8) | ((u32)qc.__x << 16) | ((u32)qd.__x << 24);
#endif
}

// accumulate one fp8 row-slice (8 feats) into 4 packed f32 pairs (v_pk_add_f32)
__device__ __forceinline__ void acc_row(uint2 r, f32x2* acc){
#if FP8_HW
  acc[0] += __builtin_amdgcn_cvt_pk_f32_fp8(r.x, false);
  acc[1] += __builtin_amdgcn_cvt_pk_f32_fp8(r.x, true);
  acc[2] += __builtin_amdgcn_cvt_pk_f32_fp8(r.y, false);
  acc[3] += __builtin_amdgcn_cvt_pk_f32_fp8(r.y, true);
#else
  float t0[4], t1[4];
  fp8x4_to_f32(r.x, t0); fp8x4_to_f32(r.y, t1);
  acc[0].x += t0[0]; acc[0].y += t0[1]; acc[1].x += t0[2]; acc[1].y += t0[3];
  acc[2].x += t1[0]; acc[2].y += t1[1]; acc[3].x += t1[2]; acc[3].y += t1[3];
#endif
}

// ---------------- fused prep: cvt_x8 | wprep3 | hist ----------------

__global__ __launch_bounds__(256) void prep_kernel(
    const float* __restrict__ x,
    const float* __restrict__ W1, const float* __restrict__ W2,
    const float* __restrict__ W3, const int* __restrict__ edst,
    uint2* __restrict__ X8, u16* __restrict__ Wp1, u16* __restrict__ Wp2,
    u16* __restrict__ Wp3, int* __restrict__ hcnt){
  __shared__ int h[NB_BKT];
  int blk = blockIdx.x;
  if (blk < PREP_CVT){
    int i = blk * 256 + threadIdx.x;             // < 1.6M exactly
    const float4* p = (const float4*)x + (size_t)i * 2;
    float4 a = p[0], b = p[1];
    uint2 o;
    o.x = f32x4_to_fp8(a.x, a.y, a.z, a.w);
    o.y = f32x4_to_fp8(b.x, b.y, b.z, b.w);
    X8[i] = o;
  } else if (blk < PREP_CVT + PREP_W){
    int b = blk - PREP_CVT;
    int which = b >> 6;
    const float* W = (which == 0) ? W1 : (which == 1) ? W2 : W3;
    u16*        Wp = (which == 0) ? Wp1 : (which == 1) ? Wp2 : Wp3;
    int idx = (b & 63) * 256 + threadIdx.x;      // 0..16383
    int j    = idx & 7;
    int lane = (idx >> 3) & 63;
    int t    = idx >> 9;
    int k0 = t & 3, n0 = t >> 2;
    int k = k0 * 32 + (lane >> 4) * 8 + j;
    int n = n0 * 16 + (lane & 15);
    Wp[idx] = bf16_rn(W[k * FEAT + n]);
  } else {
    int hb = blk - (PREP_CVT + PREP_W);
    for (int i = threadIdx.x; i < NB_BKT; i += 256) h[i] = 0;
    __syncthreads();
    int base = hb * EPB_SC;
    for (int e = base + threadIdx.x; e < base + EPB_SC; e += 256)
      atomicAdd(&h[edst[e] >> BKT_SHIFT], 1);
    __syncthreads();
    for (int i = threadIdx.x; i < NB_BKT; i += 256)
      hcnt[hb * NB_BKT + i] = h[i];
  }
}

// ---------------- CSR build: atomic-free deterministic bucket sort ----------------
// bbuf entry is one u32: low 24 bits = src id (<2^17), high 8 = dst & 255.

__global__ void hscan_kernel(int* __restrict__ hcnt, int* __restrict__ cursor){
  __shared__ int s[256];
  int b = blockIdx.x, t = threadIdx.x;
  int v[4]; int sum = 0;
  #pragma unroll
  for (int j = 0; j < 4; ++j){
    int blk = 4 * t + j;
    v[j] = (blk < NB_SC) ? hcnt[blk * NB_BKT + b] : 0;
    sum += v[j];
  }
  s[t] = sum;
  __syncthreads();
  for (int d = 1; d < 256; d <<= 1){
    int add = (t >= d) ? s[t - d] : 0;
    __syncthreads();
    s[t] += add;
    __syncthreads();
  }
  int excl = s[t] - sum;
  #pragma unroll
  for (int j = 0; j < 4; ++j){
    int blk = 4 * t + j;
    if (blk < NB_SC){ hcnt[blk * NB_BKT + b] = excl; excl += v[j]; }
  }
  if (t == 255) cursor[b] = s[255];
}

__global__ __launch_bounds__(512) void scatter_kernel(const int* __restrict__ src,
                                                      const int* __restrict__ dst,
                                                      const int* __restrict__ hcnt,
                                                      u32* __restrict__ bbuf){
  __shared__ int cur[NB_BKT];
  for (int i = threadIdx.x; i < NB_BKT; i += 512)
    cur[i] = hcnt[blockIdx.x * NB_BKT + i];
  __syncthreads();
  int base = blockIdx.x * EPB_SC;
  for (int e = base + threadIdx.x; e < base + EPB_SC; e += 512){
    int d = dst[e];
    int b = d >> BKT_SHIFT;
    int p = atomicAdd(&cur[b], 1);
    bbuf[(size_t)b * BKT_CAP + p] = (u32)src[e] | ((u32)(d & (BKT_SIZE - 1)) << 24);
  }
}

// one block per bucket: stage bucket in LDS, per-node LDS hist + scan, LDS-atomic
// scatter into an LDS segment buffer, per-node ASCENDING insertion sort (gather
// locality: all co-resident layer waves then sweep the src table low->high,
// concentrating the hot set into a moving L2-resident band), pad to mult-of-8
// (pad index 0, corrected in agg), coalesced write-out + 32 zero slack slots.
__global__ __launch_bounds__(1024) void csr_build_kernel(const u32* __restrict__ bbuf,
                                 const int* __restrict__ cursor,
                                 int* __restrict__ offs, int* __restrict__ deg,
                                 float* __restrict__ inv_deg, int* __restrict__ eidx){
  __shared__ u32 bloc[BKT_CAP];                  // 22.7 KB staged bucket
  __shared__ int seg[BKT_CAP];                   // 22.7 KB sorted segments
  __shared__ int hist[BKT_SIZE];
  __shared__ int s[BKT_SIZE];
  __shared__ int cu[BKT_SIZE];
  __shared__ int stot;
  int b = blockIdx.x;
  int t = threadIdx.x;
  int lo = b * BKT_CAP;
  int n  = cursor[b];
  for (int e = t; e < n; e += 1024) bloc[e] = bbuf[lo + e];
  if (t < BKT_SIZE) hist[t] = 0;
  __syncthreads();
  for (int e = t; e < n; e += 1024)
    atomicAdd(&hist[bloc[e] >> 24], 1);
  __syncthreads();
  int v = 0, pv = 0;
  if (t < BKT_SIZE){
    v  = hist[t];
    pv = (v + 7) & ~7;            // padded length (mult of 8)
    s[t] = pv;
  }
  __syncthreads();
  for (int d = 1; d < BKT_SIZE; d <<= 1){
    int add = (t < BKT_SIZE && t >= d) ? s[t - d] : 0;
    __syncthreads();
    if (t < BKT_SIZE && t >= d) s[t] += add;
    __syncthreads();
  }
  int excl = 0, node = -1;
  if (t < BKT_SIZE){
    excl = s[t] - pv;
    node = b * BKT_SIZE + t;
    if (node < N_NODES){
      offs[node]    = lo + excl;
      deg[node]     = v;
      inv_deg[node] = 1.0f / fmaxf((float)v, 1.0f);
      for (int p = v; p < pv; ++p) seg[excl + p] = 0;        // pad -> row 0
    }
    s[t]  = excl;
    cu[t] = 0;
    if (t == BKT_SIZE - 1) stot = excl + pv;
  }
  __syncthreads();
  for (int e = t; e < n; e += 1024){
    u32 q = bloc[e];
    int y = (int)(q >> 24);
    int p = atomicAdd(&cu[y], 1);
    seg[s[y] + p] = (int)(q & 0xFFFFFFu);
  }
  __syncthreads();
  // per-node ascending insertion sort (deterministic neighbor order)
  if (t < BKT_SIZE && node < N_NODES && v > 1){
    for (int i = 1; i < v; ++i){
      int key = seg[excl + i];
      int j = i - 1;
      while (j >= 0 && seg[excl + j] > key){
        seg[excl + j + 1] = seg[excl + j];
        --j;
      }
      seg[excl + j + 1] = key;
    }
  }
  __syncthreads();
  int tot = stot;
  for (int e = t; e < tot; e += 1024) eidx[lo + e] = seg[e];
  if (t < 32 && tot + 32 <= BKT_CAP) eidx[lo + tot + t] = 0;  // prefetch slack
}

// ---------------- fused layer: 2 waves / 16 nodes. Depth-2 pipelined gather
// -> 4KB LDS tile -> MFMA GEMM (n0 split across waves) -> emit.
// LDS tile: 16 rows x 128 cols bf16, 16B-slot swizzle: slot = row*16 + (q ^ (row&7)).

template<int SM, int OUT>   // SM: 1 = self from fp32 x, 0 = self from bf16 H
                            // OUT: 0 = relu + bf16 H + fp8 H8, 1 = fp32, no relu
__global__ __launch_bounds__(128, 8) void layer_kernel(
    const u32* __restrict__ n8,     // fp8 neighbor table, row = 32 u32
    const u16* __restrict__ hb,     // bf16 self table (SM=0)
    const float* __restrict__ xf,   // fp32 self table (SM=1)
    const int* __restrict__ offs,
    const int* __restrict__ deg,
    const float* __restrict__ inv_deg,
    const int* __restrict__ eidx,
    const u16* __restrict__ Wp,
    const float* __restrict__ bias,
    u16* __restrict__ Hout,
    u32* __restrict__ H8out,
    float* __restrict__ Fout){
  __shared__ u16 Tt[16 * FEAT];                  // 4 KB
  const int tid   = threadIdx.x;
  const int wid   = tid >> 6;                    // 0..1
  const int lane  = tid & 63;
  const int nsub  = lane >> 4;
  const int slice = lane & 15;
  const int base  = blockIdx.x * 16;             // grid = 6250 exactly
  const u32* gbase = n8 + slice * 2;

  // ---- phase 1: each wave aggregates 8 nodes (2 groups of 4) into LDS ----
  for (int g = 0; g < 2; ++g){
    const int rrow = wid * 8 + (g << 2) + nsub;  // 0..15
    const int node = base + rrow;
    const int start = offs[node];
    const int cnt   = deg[node];
    const int pcnt  = (cnt + 7) & ~7;
    const int* ep = eidx + start;                // 32-B aligned (pad-8 CSR)

    f32x2 acc[4];
    #pragma unroll
    for (int j = 0; j < 4; ++j) acc[j] = (f32x2){0.f, 0.f};

    // prologue: iter-0 indices + rows (guarded), iter-1 indices (addr-safe;
    // values only used as gather addresses when those iterations exist).
    uint2 rc[8];
    #pragma unroll
    for (int j = 0; j < 8; ++j) rc[j] = make_uint2(0u, 0u);
    if (pcnt > 0){
      uint4 q0 = *(const uint4*)ep;
      uint4 q1 = *(const uint4*)(ep + 4);
      rc[0] = *(const uint2*)(gbase + (size_t)q0.x * 32);
      rc[1] = *(const uint2*)(gbase + (size_t)q0.y * 32);
      rc[2] = *(const uint2*)(gbase + (size_t)q0.z * 32);
      rc[3] = *(const uint2*)(gbase + (size_t)q0.w * 32);
      rc[4] = *(const uint2*)(gbase + (size_t)q1.x * 32);
      rc[5] = *(const uint2*)(gbase + (size_t)q1.y * 32);
      rc[6] = *(const uint2*)(gbase + (size_t)q1.z * 32);
      rc[7] = *(const uint2*)(gbase + (size_t)q1.w * 32);
    }
    uint4 qn1 = *(const uint4*)(ep + 8);
    uint4 qn2 = *(const uint4*)(ep + 12);

    for (int e = 0; e < pcnt; e += 8){
      uint2 rn[8];
      rn[0] = *(const uint2*)(gbase + (size_t)qn1.x * 32);
      rn[1] = *(const uint2*)(gbase + (size_t)qn1.y * 32);
      rn[2] = *(const uint2*)(gbase + (size_t)qn1.z * 32);
      rn[3] = *(const uint2*)(gbase + (size_t)qn1.w * 32);
      rn[4] = *(const uint2*)(gbase + (size_t)qn2.x * 32);
      rn[5] = *(const uint2*)(gbase + (size_t)qn2.y * 32);
      rn[6] = *(const uint2*)(gbase + (size_t)qn2.z * 32);
      rn[7] = *(const uint2*)(gbase + (size_t)qn2.w * 32);
      qn1 = *(const uint4*)(ep + e + 16);
      qn2 = *(const uint4*)(ep + e + 20);
      #pragma unroll
      for (int j = 0; j < 8; ++j) acc_row(rc[j], acc);
      #pragma unroll
      for (int j = 0; j < 8; ++j) rc[j] = rn[j];
    }

    if (pcnt > cnt){                             // subtract pad contribution (row 0)
      float f = (float)(pcnt - cnt);
      uint2 rz = *(const uint2*)gbase;
      f32x2 z[4];
      #pragma unroll
      for (int j = 0; j < 4; ++j) z[j] = (f32x2){0.f, 0.f};
      acc_row(rz, z);
      #pragma unroll
      for (int j = 0; j < 4; ++j) acc[j] -= f * z[j];
    }

    const float w = inv_deg[node];
    float self[8];
    if (SM == 1){
      const float* sp = xf + (size_t)node * FEAT + slice * 8;
      float4 a = *(const float4*)sp;
      float4 b = *(const float4*)(sp + 4);
      self[0]=a.x; self[1]=a.y; self[2]=a.z; self[3]=a.w;
      self[4]=b.x; self[5]=b.y; self[6]=b.z; self[7]=b.w;
    } else {
      const u16* sp = hb + (size_t)node * FEAT + slice * 8;
      uint4 s0 = *(const uint4*)sp;
      self[0]=bf16_lo(s0.x); self[1]=bf16_hi(s0.x); self[2]=bf16_lo(s0.y); self[3]=bf16_hi(s0.y);
      self[4]=bf16_lo(s0.z); self[5]=bf16_hi(s0.z); self[6]=bf16_lo(s0.w); self[7]=bf16_hi(s0.w);
    }
    uint4 o;
    o.x = (u32)bf16_rn(self[0] + w*acc[0].x) | ((u32)bf16_rn(self[1] + w*acc[0].y) << 16);
    o.y = (u32)bf16_rn(self[2] + w*acc[1].x) | ((u32)bf16_rn(self[3] + w*acc[1].y) << 16);
    o.z = (u32)bf16_rn(self[4] + w*acc[2].x) | ((u32)bf16_rn(self[5] + w*acc[2].y) << 16);
    o.w = (u32)bf16_rn(self[6] + w*acc[3].x) | ((u32)bf16_rn(self[7] + w*acc[3].y) << 16);
    ((uint4*)Tt)[rrow * 16 + (slice ^ (rrow & 7))] = o;
  }
  __syncthreads();

  // ---- phase 2: GEMM, 16 rows x 128 cols; wave w computes cols [w*64, w*64+64) ----
  const int quad = lane >> 4;
  const int c    = lane & 15;

  bf16x8 A[4];
  #pragma unroll
  for (int k0 = 0; k0 < 4; ++k0){
    uint4 t = ((const uint4*)Tt)[c * 16 + ((quad + k0 * 4) ^ (c & 7))];
    A[k0] = *(const bf16x8*)&t;
  }
  if (OUT == 0) __syncthreads();                 // both waves' A reads done before overwrite

  f32x4 acc2[4];
  #pragma unroll
  for (int i = 0; i < 4; ++i) acc2[i] = (f32x4){0.f, 0.f, 0.f, 0.f};
  #pragma unroll
  for (int i = 0; i < 4; ++i){
    int n0 = wid * 4 + i;
    #pragma unroll
    for (int k0 = 0; k0 < 4; ++k0){
      bf16x8 b = *(const bf16x8*)(Wp + (size_t)(((n0 << 2) | k0) * 64 + lane) * 8);
      acc2[i] = __builtin_amdgcn_mfma_f32_16x16x32_bf16(A[k0], b, acc2[i], 0, 0, 0);
    }
  }
  #pragma unroll
  for (int i = 0; i < 4; ++i){
    int n0 = wid * 4 + i;
    float bv = bias[n0 * 16 + c];
    #pragma unroll
    for (int r = 0; r < 4; ++r){
      int rr  = quad * 4 + r;
      int col = n0 * 16 + c;
      if (OUT == 1){
        Fout[(size_t)(base + rr) * FEAT + col] = acc2[i][r] + bv;
      } else {
        float v = fmaxf(acc2[i][r] + bv, 0.f);
        Tt[rr * FEAT + (col ^ ((rr & 7) << 3))] = bf16_rn(v);
      }
    }
  }

  if (OUT == 0){
    __syncthreads();
    #pragma unroll
    for (int it = 0; it < 2; ++it){
      int p  = it * 128 + tid;                   // 0..255 16B-slots
      int rr = p >> 4, qq = p & 15;
      int node = base + rr;
      uint4 d = ((const uint4*)Tt)[rr * 16 + (qq ^ (rr & 7))];
      *(uint4*)(Hout + (size_t)node * FEAT + qq * 8) = d;
      uint2 o8;
      o8.x = f32x4_to_fp8(bf16_lo(d.x), bf16_hi(d.x), bf16_lo(d.y), bf16_hi(d.y));
      o8.y = f32x4_to_fp8(bf16_lo(d.z), bf16_hi(d.z), bf16_lo(d.w), bf16_hi(d.w));
      *(uint2*)(H8out + (size_t)node * 32 + qq * 2) = o8;
    }
  }
}

// ---------------- launch ----------------

static inline size_t align_up(size_t x){ return (x + 255) & ~(size_t)255; }

extern "C" void kernel_launch(void* const* d_in, const int* in_sizes, int n_in,
                              void* d_out, int out_size, void* d_ws, size_t ws_size,
                              hipStream_t stream){
  const float* x  = (const float*)d_in[0];
  const float* W1 = (const float*)d_in[1];
  const float* b1 = (const float*)d_in[2];
  const float* W2 = (const float*)d_in[3];
  const float* b2 = (const float*)d_in[4];
  const float* W3 = (const float*)d_in[5];
  const float* b3 = (const float*)d_in[6];
  const int* esrc = (const int*)d_in[7];
  const int* edst = (const int*)d_in[8];

  char* w = (char*)d_ws;
  int*   deg     = (int*)w;    w += align_up((size_t)N_NODES * 4);
  int*   offs    = (int*)w;    w += align_up((size_t)N_NODES * 4);
  float* inv_deg = (float*)w;  w += align_up((size_t)N_NODES * 4);
  int*   eidx    = (int*)w;    w += align_up((size_t)NB_BKT * BKT_CAP * 4);  // 8.86 MB
  u16*   Wp1     = (u16*)w;    w += align_up((size_t)16384 * 2);
  u16*   Wp2     = (u16*)w;    w += align_up((size_t)16384 * 2);
  u16*   Wp3     = (u16*)w;    w += align_up((size_t)16384 * 2);
  u16*   Hb      = (u16*)w;    w += align_up((size_t)N_NODES * FEAT * 2);    // 25.6 MB
  u32*   H8b     = (u32*)w;    w += align_up((size_t)N_NODES * 32 * 4);      // 12.8 MB

  // scratch aliases: bbuf (8.86 MB, u32-packed) in Hb; cursor+hcnt (1.26 MB) in
  // H8b. Both dead before Hb/H8b are first written (layer 2).
  u32* bbuf   = (u32*)Hb;
  int* cursor = (int*)H8b;
  int* hcnt   = (int*)((char*)H8b + align_up((size_t)NB_BKT * 4));

  // d_out (51.2 MB) hosts during layers 1-2: Ha bf16 [0,25.6) | H8a fp8 [25.6,38.4) | X8 fp8 [38.4,51.2)
  // layer 3 overwrites all of d_out with the fp32 result.
  u16* Ha  = (u16*)d_out;
  u32* H8a = (u32*)((char*)d_out + (size_t)N_NODES * FEAT * 2);
  u32* X8  = (u32*)((char*)d_out + (size_t)N_NODES * FEAT * 3);

  // prep (cvt_x8 | wprep | hist) then CSR bucket sort (neighbor lists sorted asc)
  prep_kernel<<<PREP_CVT + PREP_W + PREP_H, 256, 0, stream>>>(
      x, W1, W2, W3, edst, (uint2*)X8, Wp1, Wp2, Wp3, hcnt);
  hscan_kernel<<<NB_BKT, 256, 0, stream>>>(hcnt, cursor);
  scatter_kernel<<<NB_SC, 512, 0, stream>>>(esrc, edst, hcnt, bbuf);
  csr_build_kernel<<<NB_BKT, 1024, 0, stream>>>(bbuf, cursor, offs, deg, inv_deg, eidx);

  const int LAYER_BLOCKS = N_NODES / 16;          // 6250 exactly, 2 waves each

  // layer 1: neighbors X8, self fp32 x -> Ha + H8a
  layer_kernel<1, 0><<<LAYER_BLOCKS, 128, 0, stream>>>(
      X8, (const u16*)nullptr, x, offs, deg, inv_deg, eidx, Wp1, b1,
      Ha, H8a, (float*)nullptr);

  // layer 2: neighbors H8a, self Ha -> Hb + H8b
  layer_kernel<0, 0><<<LAYER_BLOCKS, 128, 0, stream>>>(
      H8a, Ha, (const float*)nullptr, offs, deg, inv_deg, eidx, Wp2, b2,
      Hb, H8b, (float*)nullptr);

  // layer 3: neighbors H8b, self Hb -> fp32 d_out, no relu
  layer_kernel<0, 1><<<LAYER_BLOCKS, 128, 0, stream>>>(
      H8b, Hb, (const float*)nullptr, offs, deg, inv_deg, eidx, Wp3, b3,
      (u16*)nullptr, (u32*)nullptr, (float*)d_out);

  (void)in_sizes; (void)n_in; (void)out_size; (void)ws_size; (void)w;
}

// Round 7
// 295.429 us; speedup vs baseline: 1.1331x; 1.1331x over previous
//
#include <hip/hip_runtime.h>
#include <hip/hip_bf16.h>
#include <stdint.h>

#if __has_builtin(__builtin_amdgcn_cvt_pk_f32_fp8) && __has_builtin(__builtin_amdgcn_cvt_pk_fp8_f32)
#define FP8_HW 1
#else
#define FP8_HW 0
#include <hip/hip_fp8.h>
#endif

#define N_NODES 100000
#define N_EDGES 1600000
#define FEAT 128

#define BKT_SHIFT 8
#define BKT_SIZE  256
#define NB_BKT    391          // ceil(N_NODES / 256)
#define BKT_CAP   5664         // pad-8 mean 4982 + >9-sigma headroom, mult of 8
#define NB_SC     800          // blocks in edge scatter pass
#define EPB_SC    2000         // edges per block (800*2000 = 1.6M exactly)

#define PREP_CVT 6250          // cvt_x8 blocks (6250*256 = 1.6M rows of 8 floats)
#define PREP_W   192           // wprep blocks

typedef uint16_t u16;
typedef uint32_t u32;
typedef __attribute__((ext_vector_type(8))) short bf16x8;
typedef __attribute__((ext_vector_type(4))) float f32x4;
typedef __attribute__((ext_vector_type(2))) float f32x2;

__device__ __forceinline__ u16 bf16_rn(float f){
  u32 u = __float_as_uint(f);
  u += 0x7FFFu + ((u >> 16) & 1u);
  return (u16)(u >> 16);
}
__device__ __forceinline__ float bf16_lo(u32 p){ return __uint_as_float(p << 16); }
__device__ __forceinline__ float bf16_hi(u32 p){ return __uint_as_float(p & 0xFFFF0000u); }

__device__ __forceinline__ void fp8x4_to_f32(u32 w, float* o){
#if FP8_HW
  f32x2 a = __builtin_amdgcn_cvt_pk_f32_fp8(w, false);
  f32x2 b = __builtin_amdgcn_cvt_pk_f32_fp8(w, true);
  o[0] = a.x; o[1] = a.y; o[2] = b.x; o[3] = b.y;
#else
  #pragma unroll
  for (int i = 0; i < 4; ++i){
    __hip_fp8_e4m3 t; t.__x = (uint8_t)((w >> (8 * i)) & 0xFF);
    o[i] = (float)t;
  }
#endif
}
__device__ __forceinline__ u32 f32x4_to_fp8(float a, float b, float c, float d){
#if FP8_HW
  u32 r = __builtin_amdgcn_cvt_pk_fp8_f32(a, b, 0, false);
  r = __builtin_amdgcn_cvt_pk_fp8_f32(c, d, r, true);
  return r;
#else
  __hip_fp8_e4m3 qa(a), qb(b), qc(c), qd(d);
  return (u32)qa.__x | ((u32)qb.__x << 8) | ((u32)qc.__x << 16) | ((u32)qd.__x << 24);
#endif
}

// accumulate one fp8 row-slice (8 feats) into 4 packed f32 pairs (v_pk_add_f32)
__device__ __forceinline__ void acc_row(uint2 r, f32x2* acc){
#if FP8_HW
  acc[0] += __builtin_amdgcn_cvt_pk_f32_fp8(r.x, false);
  acc[1] += __builtin_amdgcn_cvt_pk_f32_fp8(r.x, true);
  acc[2] += __builtin_amdgcn_cvt_pk_f32_fp8(r.y, false);
  acc[3] += __builtin_amdgcn_cvt_pk_f32_fp8(r.y, true);
#else
  float t0[4], t1[4];
  fp8x4_to_f32(r.x, t0); fp8x4_to_f32(r.y, t1);
  acc[0].x += t0[0]; acc[0].y += t0[1]; acc[1].x += t0[2]; acc[1].y += t0[3];
  acc[2].x += t1[0]; acc[2].y += t1[1]; acc[3].x += t1[2]; acc[3].y += t1[3];
#endif
}

// ---------------- fused prep: cvt_x8 | wprep3 | cursor-zero ----------------

__global__ __launch_bounds__(256) void prep_kernel(
    const float* __restrict__ x,
    const float* __restrict__ W1, const float* __restrict__ W2,
    const float* __restrict__ W3,
    uint2* __restrict__ X8, u16* __restrict__ Wp1, u16* __restrict__ Wp2,
    u16* __restrict__ Wp3, int* __restrict__ gcur){
  int blk = blockIdx.x;
  if (blk < PREP_CVT){
    int i = blk * 256 + threadIdx.x;             // < 1.6M exactly
    const float4* p = (const float4*)x + (size_t)i * 2;
    float4 a = p[0], b = p[1];
    uint2 o;
    o.x = f32x4_to_fp8(a.x, a.y, a.z, a.w);
    o.y = f32x4_to_fp8(b.x, b.y, b.z, b.w);
    X8[i] = o;
  } else if (blk < PREP_CVT + PREP_W){
    int b = blk - PREP_CVT;
    int which = b >> 6;
    const float* W = (which == 0) ? W1 : (which == 1) ? W2 : W3;
    u16*        Wp = (which == 0) ? Wp1 : (which == 1) ? Wp2 : Wp3;
    int idx = (b & 63) * 256 + threadIdx.x;      // 0..16383
    int j    = idx & 7;
    int lane = (idx >> 3) & 63;
    int t    = idx >> 9;
    int k0 = t & 3, n0 = t >> 2;
    int k = k0 * 32 + (lane >> 4) * 8 + j;
    int n = n0 * 16 + (lane & 15);
    Wp[idx] = bf16_rn(W[k * FEAT + n]);
  } else {
    for (int i = threadIdx.x; i < NB_BKT; i += 256) gcur[i] = 0;
  }
}

// ---------------- scatter: fused hist + global range-reserve + LDS-cursor write --
// Replaces hist+hscan+scatter. Per block: LDS histogram of its 2000 edges, ONE
// global atomicAdd per touched bucket reserves a contiguous range (block-private
// consecutive writes -> coalesced), then LDS-cursor scatter. Within-node neighbor
// order becomes nondeterministic (reservation race) — only perturbs fp32 sum
// order, validated within tolerance (R3 passed with identical absmax).
// bbuf entry: low 24 bits = src id (<2^17), high 8 = dst & 255.
// After this kernel, gcur[b] = bucket b's total count (csr_build's cursor input).

__global__ __launch_bounds__(512) void scatter_kernel(const int* __restrict__ src,
                                                      const int* __restrict__ dst,
                                                      int* __restrict__ gcur,
                                                      u32* __restrict__ bbuf){
  __shared__ int cur[NB_BKT];
  int t = threadIdx.x;
  for (int i = t; i < NB_BKT; i += 512) cur[i] = 0;
  __syncthreads();
  int base = blockIdx.x * EPB_SC;
  int dv[4], bv[4];
  #pragma unroll
  for (int j = 0; j < 4; ++j){
    int o = j * 512 + t;
    dv[j] = (o < EPB_SC) ? dst[base + o] : -1;
    bv[j] = (dv[j] >= 0) ? (dv[j] >> BKT_SHIFT) : 0;
    if (dv[j] >= 0) atomicAdd(&cur[bv[j]], 1);
  }
  __syncthreads();
  for (int i = t; i < NB_BKT; i += 512){
    int c = cur[i];
    cur[i] = c ? atomicAdd(&gcur[i], c) : 0;    // reserve contiguous range
  }
  __syncthreads();
  #pragma unroll
  for (int j = 0; j < 4; ++j){
    int o = j * 512 + t;
    if (dv[j] >= 0){
      int p = atomicAdd(&cur[bv[j]], 1);
      bbuf[(size_t)bv[j] * BKT_CAP + p] =
          (u32)src[base + o] | ((u32)(dv[j] & (BKT_SIZE - 1)) << 24);
    }
  }
}

// one block per bucket: stage bucket in LDS (single global read), per-node LDS
// hist + scan + LDS-atomic scatter. Segments padded to multiples of 8 (pad
// index 0, corrected in agg). 32 zero slack slots past the bucket's padded end
// make prefetch over-reads safe. (Insertion sort removed: +35us for a confirmed
// locality null — resident blocks sweep out of phase, so sorted lists don't
// concentrate the gather working set.)
__global__ __launch_bounds__(1024) void csr_build_kernel(const u32* __restrict__ bbuf,
                                 const int* __restrict__ cursor,
                                 int* __restrict__ offs, int* __restrict__ deg,
                                 float* __restrict__ inv_deg, int* __restrict__ eidx){
  __shared__ u32 bloc[BKT_CAP];                  // 22.7 KB
  __shared__ int hist[BKT_SIZE];
  __shared__ int s[BKT_SIZE];
  __shared__ int cu[BKT_SIZE];
  __shared__ int stot;
  int b = blockIdx.x;
  int t = threadIdx.x;
  int lo = b * BKT_CAP;
  int n  = cursor[b];
  for (int e = t; e < n; e += 1024) bloc[e] = bbuf[lo + e];
  if (t < BKT_SIZE) hist[t] = 0;
  __syncthreads();
  for (int e = t; e < n; e += 1024)
    atomicAdd(&hist[bloc[e] >> 24], 1);
  __syncthreads();
  int v = 0, pv = 0;
  if (t < BKT_SIZE){
    v  = hist[t];
    pv = (v + 7) & ~7;            // padded length (mult of 8)
    s[t] = pv;
  }
  __syncthreads();
  for (int d = 1; d < BKT_SIZE; d <<= 1){
    int add = (t < BKT_SIZE && t >= d) ? s[t - d] : 0;
    __syncthreads();
    if (t < BKT_SIZE && t >= d) s[t] += add;
    __syncthreads();
  }
  if (t < BKT_SIZE){
    int excl = s[t] - pv;
    int node = b * BKT_SIZE + t;
    if (node < N_NODES){
      offs[node]    = lo + excl;
      deg[node]     = v;
      inv_deg[node] = 1.0f / fmaxf((float)v, 1.0f);
      for (int p = v; p < pv; ++p) eidx[lo + excl + p] = 0;   // pad -> row 0
    }
    s[t]  = excl;
    cu[t] = 0;
    if (t == BKT_SIZE - 1) stot = excl + pv;
  }
  __syncthreads();
  for (int e = t; e < n; e += 1024){
    u32 q = bloc[e];
    int y = (int)(q >> 24);
    int p = atomicAdd(&cu[y], 1);
    eidx[lo + s[y] + p] = (int)(q & 0xFFFFFFu);
  }
  int tot = stot;
  if (t < 32 && tot + 32 <= BKT_CAP) eidx[lo + tot + t] = 0;  // prefetch slack
}

// ---------------- fused layer: 2 waves / 16 nodes. Depth-2 pipelined gather
// -> 4KB LDS tile -> MFMA GEMM (n0 split across waves) -> emit.
// LDS tile: 16 rows x 128 cols bf16, 16B-slot swizzle: slot = row*16 + (q ^ (row&7)).
// Layer time is pinned at ~51us by per-CU miss-tracking capacity x fill latency
// (invariant under occupancy 31->62%, MLP 5->10, divergence equalization, sorted
// lists) — left unchanged.

template<int SM, int OUT>   // SM: 1 = self from fp32 x, 0 = self from bf16 H
                            // OUT: 0 = relu + bf16 H + fp8 H8, 1 = fp32, no relu
__global__ __launch_bounds__(128, 8) void layer_kernel(
    const u32* __restrict__ n8,     // fp8 neighbor table, row = 32 u32
    const u16* __restrict__ hb,     // bf16 self table (SM=0)
    const float* __restrict__ xf,   // fp32 self table (SM=1)
    const int* __restrict__ offs,
    const int* __restrict__ deg,
    const float* __restrict__ inv_deg,
    const int* __restrict__ eidx,
    const u16* __restrict__ Wp,
    const float* __restrict__ bias,
    u16* __restrict__ Hout,
    u32* __restrict__ H8out,
    float* __restrict__ Fout){
  __shared__ u16 Tt[16 * FEAT];                  // 4 KB
  const int tid   = threadIdx.x;
  const int wid   = tid >> 6;                    // 0..1
  const int lane  = tid & 63;
  const int nsub  = lane >> 4;
  const int slice = lane & 15;
  const int base  = blockIdx.x * 16;             // grid = 6250 exactly
  const u32* gbase = n8 + slice * 2;

  // ---- phase 1: each wave aggregates 8 nodes (2 groups of 4) into LDS ----
  for (int g = 0; g < 2; ++g){
    const int rrow = wid * 8 + (g << 2) + nsub;  // 0..15
    const int node = base + rrow;
    const int start = offs[node];
    const int cnt   = deg[node];
    const int pcnt  = (cnt + 7) & ~7;
    const int* ep = eidx + start;                // 32-B aligned (pad-8 CSR)

    f32x2 acc[4];
    #pragma unroll
    for (int j = 0; j < 4; ++j) acc[j] = (f32x2){0.f, 0.f};

    // prologue: iter-0 indices + rows (guarded), iter-1 indices (addr-safe;
    // values only used as gather addresses when those iterations exist).
    uint2 rc[8];
    #pragma unroll
    for (int j = 0; j < 8; ++j) rc[j] = make_uint2(0u, 0u);
    if (pcnt > 0){
      uint4 q0 = *(const uint4*)ep;
      uint4 q1 = *(const uint4*)(ep + 4);
      rc[0] = *(const uint2*)(gbase + (size_t)q0.x * 32);
      rc[1] = *(const uint2*)(gbase + (size_t)q0.y * 32);
      rc[2] = *(const uint2*)(gbase + (size_t)q0.z * 32);
      rc[3] = *(const uint2*)(gbase + (size_t)q0.w * 32);
      rc[4] = *(const uint2*)(gbase + (size_t)q1.x * 32);
      rc[5] = *(const uint2*)(gbase + (size_t)q1.y * 32);
      rc[6] = *(const uint2*)(gbase + (size_t)q1.z * 32);
      rc[7] = *(const uint2*)(gbase + (size_t)q1.w * 32);
    }
    uint4 qn1 = *(const uint4*)(ep + 8);
    uint4 qn2 = *(const uint4*)(ep + 12);

    for (int e = 0; e < pcnt; e += 8){
      uint2 rn[8];
      rn[0] = *(const uint2*)(gbase + (size_t)qn1.x * 32);
      rn[1] = *(const uint2*)(gbase + (size_t)qn1.y * 32);
      rn[2] = *(const uint2*)(gbase + (size_t)qn1.z * 32);
      rn[3] = *(const uint2*)(gbase + (size_t)qn1.w * 32);
      rn[4] = *(const uint2*)(gbase + (size_t)qn2.x * 32);
      rn[5] = *(const uint2*)(gbase + (size_t)qn2.y * 32);
      rn[6] = *(const uint2*)(gbase + (size_t)qn2.z * 32);
      rn[7] = *(const uint2*)(gbase + (size_t)qn2.w * 32);
      qn1 = *(const uint4*)(ep + e + 16);
      qn2 = *(const uint4*)(ep + e + 20);
      #pragma unroll
      for (int j = 0; j < 8; ++j) acc_row(rc[j], acc);
      #pragma unroll
      for (int j = 0; j < 8; ++j) rc[j] = rn[j];
    }

    if (pcnt > cnt){                             // subtract pad contribution (row 0)
      float f = (float)(pcnt - cnt);
      uint2 rz = *(const uint2*)gbase;
      f32x2 z[4];
      #pragma unroll
      for (int j = 0; j < 4; ++j) z[j] = (f32x2){0.f, 0.f};
      acc_row(rz, z);
      #pragma unroll
      for (int j = 0; j < 4; ++j) acc[j] -= f * z[j];
    }

    const float w = inv_deg[node];
    float self[8];
    if (SM == 1){
      const float* sp = xf + (size_t)node * FEAT + slice * 8;
      float4 a = *(const float4*)sp;
      float4 b = *(const float4*)(sp + 4);
      self[0]=a.x; self[1]=a.y; self[2]=a.z; self[3]=a.w;
      self[4]=b.x; self[5]=b.y; self[6]=b.z; self[7]=b.w;
    } else {
      const u16* sp = hb + (size_t)node * FEAT + slice * 8;
      uint4 s0 = *(const uint4*)sp;
      self[0]=bf16_lo(s0.x); self[1]=bf16_hi(s0.x); self[2]=bf16_lo(s0.y); self[3]=bf16_hi(s0.y);
      self[4]=bf16_lo(s0.z); self[5]=bf16_hi(s0.z); self[6]=bf16_lo(s0.w); self[7]=bf16_hi(s0.w);
    }
    uint4 o;
    o.x = (u32)bf16_rn(self[0] + w*acc[0].x) | ((u32)bf16_rn(self[1] + w*acc[0].y) << 16);
    o.y = (u32)bf16_rn(self[2] + w*acc[1].x) | ((u32)bf16_rn(self[3] + w*acc[1].y) << 16);
    o.z = (u32)bf16_rn(self[4] + w*acc[2].x) | ((u32)bf16_rn(self[5] + w*acc[2].y) << 16);
    o.w = (u32)bf16_rn(self[6] + w*acc[3].x) | ((u32)bf16_rn(self[7] + w*acc[3].y) << 16);
    ((uint4*)Tt)[rrow * 16 + (slice ^ (rrow & 7))] = o;
  }
  __syncthreads();

  // ---- phase 2: GEMM, 16 rows x 128 cols; wave w computes cols [w*64, w*64+64) ----
  const int quad = lane >> 4;
  const int c    = lane & 15;

  bf16x8 A[4];
  #pragma unroll
  for (int k0 = 0; k0 < 4; ++k0){
    uint4 t = ((const uint4*)Tt)[c * 16 + ((quad + k0 * 4) ^ (c & 7))];
    A[k0] = *(const bf16x8*)&t;
  }
  if (OUT == 0) __syncthreads();                 // both waves' A reads done before overwrite

  f32x4 acc2[4];
  #pragma unroll
  for (int i = 0; i < 4; ++i) acc2[i] = (f32x4){0.f, 0.f, 0.f, 0.f};
  #pragma unroll
  for (int i = 0; i < 4; ++i){
    int n0 = wid * 4 + i;
    #pragma unroll
    for (int k0 = 0; k0 < 4; ++k0){
      bf16x8 b = *(const bf16x8*)(Wp + (size_t)(((n0 << 2) | k0) * 64 + lane) * 8);
      acc2[i] = __builtin_amdgcn_mfma_f32_16x16x32_bf16(A[k0], b, acc2[i], 0, 0, 0);
    }
  }
  #pragma unroll
  for (int i = 0; i < 4; ++i){
    int n0 = wid * 4 + i;
    float bv = bias[n0 * 16 + c];
    #pragma unroll
    for (int r = 0; r < 4; ++r){
      int rr  = quad * 4 + r;
      int col = n0 * 16 + c;
      if (OUT == 1){
        Fout[(size_t)(base + rr) * FEAT + col] = acc2[i][r] + bv;
      } else {
        float v = fmaxf(acc2[i][r] + bv, 0.f);
        Tt[rr * FEAT + (col ^ ((rr & 7) << 3))] = bf16_rn(v);
      }
    }
  }

  if (OUT == 0){
    __syncthreads();
    #pragma unroll
    for (int it = 0; it < 2; ++it){
      int p  = it * 128 + tid;                   // 0..255 16B-slots
      int rr = p >> 4, qq = p & 15;
      int node = base + rr;
      uint4 d = ((const uint4*)Tt)[rr * 16 + (qq ^ (rr & 7))];
      *(uint4*)(Hout + (size_t)node * FEAT + qq * 8) = d;
      uint2 o8;
      o8.x = f32x4_to_fp8(bf16_lo(d.x), bf16_hi(d.x), bf16_lo(d.y), bf16_hi(d.y));
      o8.y = f32x4_to_fp8(bf16_lo(d.z), bf16_hi(d.z), bf16_lo(d.w), bf16_hi(d.w));
      *(uint2*)(H8out + (size_t)node * 32 + qq * 2) = o8;
    }
  }
}

// ---------------- launch ----------------

static inline size_t align_up(size_t x){ return (x + 255) & ~(size_t)255; }

extern "C" void kernel_launch(void* const* d_in, const int* in_sizes, int n_in,
                              void* d_out, int out_size, void* d_ws, size_t ws_size,
                              hipStream_t stream){
  const float* x  = (const float*)d_in[0];
  const float* W1 = (const float*)d_in[1];
  const float* b1 = (const float*)d_in[2];
  const float* W2 = (const float*)d_in[3];
  const float* b2 = (const float*)d_in[4];
  const float* W3 = (const float*)d_in[5];
  const float* b3 = (const float*)d_in[6];
  const int* esrc = (const int*)d_in[7];
  const int* edst = (const int*)d_in[8];

  char* w = (char*)d_ws;
  int*   deg     = (int*)w;    w += align_up((size_t)N_NODES * 4);
  int*   offs    = (int*)w;    w += align_up((size_t)N_NODES * 4);
  float* inv_deg = (float*)w;  w += align_up((size_t)N_NODES * 4);
  int*   eidx    = (int*)w;    w += align_up((size_t)NB_BKT * BKT_CAP * 4);  // 8.86 MB
  u16*   Wp1     = (u16*)w;    w += align_up((size_t)16384 * 2);
  u16*   Wp2     = (u16*)w;    w += align_up((size_t)16384 * 2);
  u16*   Wp3     = (u16*)w;    w += align_up((size_t)16384 * 2);
  u16*   Hb      = (u16*)w;    w += align_up((size_t)N_NODES * FEAT * 2);    // 25.6 MB
  u32*   H8b     = (u32*)w;    w += align_up((size_t)N_NODES * 32 * 4);      // 12.8 MB

  // scratch aliases: bbuf (8.86 MB, u32-packed) in Hb; gcur (1.6 KB) in H8b.
  // Both dead before Hb/H8b are first written (layer 2).
  u32* bbuf = (u32*)Hb;
  int* gcur = (int*)H8b;

  // d_out (51.2 MB) hosts during layers 1-2: Ha bf16 [0,25.6) | H8a fp8 [25.6,38.4) | X8 fp8 [38.4,51.2)
  // layer 3 overwrites all of d_out with the fp32 result.
  u16* Ha  = (u16*)d_out;
  u32* H8a = (u32*)((char*)d_out + (size_t)N_NODES * FEAT * 2);
  u32* X8  = (u32*)((char*)d_out + (size_t)N_NODES * FEAT * 3);

  // prep (cvt_x8 | wprep | cursor-zero) -> scatter (hist+reserve fused) -> csr_build
  prep_kernel<<<PREP_CVT + PREP_W + 1, 256, 0, stream>>>(
      x, W1, W2, W3, (uint2*)X8, Wp1, Wp2, Wp3, gcur);
  scatter_kernel<<<NB_SC, 512, 0, stream>>>(esrc, edst, gcur, bbuf);
  csr_build_kernel<<<NB_BKT, 1024, 0, stream>>>(bbuf, gcur, offs, deg, inv_deg, eidx);

  const int LAYER_BLOCKS = N_NODES / 16;          // 6250 exactly, 2 waves each

  // layer 1: neighbors X8, self fp32 x -> Ha + H8a
  layer_kernel<1, 0><<<LAYER_BLOCKS, 128, 0, stream>>>(
      X8, (const u16*)nullptr, x, offs, deg, inv_deg, eidx, Wp1, b1,
      Ha, H8a, (float*)nullptr);

  // layer 2: neighbors H8a, self Ha -> Hb + H8b
  layer_kernel<0, 0><<<LAYER_BLOCKS, 128, 0, stream>>>(
      H8a, Ha, (const float*)nullptr, offs, deg, inv_deg, eidx, Wp2, b2,
      Hb, H8b, (float*)nullptr);

  // layer 3: neighbors H8b, self Hb -> fp32 d_out, no relu
  layer_kernel<0, 1><<<LAYER_BLOCKS, 128, 0, stream>>>(
      H8b, Hb, (const float*)nullptr, offs, deg, inv_deg, eidx, Wp3, b3,
      (u16*)nullptr, (u32*)nullptr, (float*)d_out);

  (void)in_sizes; (void)n_in; (void)out_size; (void)ws_size; (void)w;
}